// Round 4
// baseline (358.569 us; speedup 1.0000x reference)
//
#include <hip/hip_runtime.h>
#include <hip/hip_bf16.h>
#include <stdint.h>

// VQ nearest-neighbor: B=8192 z-rows vs K=8192 codes, D=256 (f32 in/out).
// Round 4: round-2 proven schedule (single static LDS tile, stage->bar->
// compute->bar) + round-3 proven pieces (fused A|B [128][64] tile, both-side
// XOR granule swizzle => 0 bank conflicts, hi-only fp16 MFMA, top-2 per
// 64-col chunk, exact f64 re-rank of per-wave top-2, gather).

#define NB 8192
#define NK 8192
#define ND 256
#define NCHUNK (NK / 64)   // 128 chunks/row, 2 candidates each -> 256 entries

typedef __attribute__((ext_vector_type(4))) _Float16 half4;
typedef __attribute__((ext_vector_type(8))) _Float16 half8;
typedef __attribute__((ext_vector_type(4))) float f32x4;
typedef unsigned long long u64;

__device__ __forceinline__ unsigned int fkey(float f) {
  unsigned int i = __float_as_uint(f);
  return (i & 0x80000000u) ? ~i : (i | 0x80000000u);  // monotone f32 -> u32
}

__device__ __forceinline__ void gload_lds16(const void* g, void* l) {
  __builtin_amdgcn_global_load_lds(
      (const __attribute__((address_space(1))) unsigned int*)g,
      (__attribute__((address_space(3))) unsigned int*)l, 16, 0, 0);
}

__device__ __forceinline__ void top2_ins(u64 v, u64& b1, u64& b2) {
  if (v < b1) { b2 = b1; b1 = v; }
  else if (v < b2) { b2 = v; }
}

__device__ __forceinline__ void top2_merge(int s, u64& b1, u64& b2) {
  u64 p1 = __shfl_xor(b1, s, 64);
  u64 p2 = __shfl_xor(b2, s, 64);
  u64 hi = b1 > p1 ? b1 : p1;
  u64 lo2 = b2 < p2 ? b2 : p2;
  b1 = b1 < p1 ? b1 : p1;
  b2 = hi < lo2 ? hi : lo2;
}

// ---- prep: one wave per row; f32 -> f16 hi; e-rows also reduce e_sq (f64) ----
__global__ __launch_bounds__(256) void prep(const float4* __restrict__ z4,
                                            const float4* __restrict__ e4,
                                            half4* __restrict__ zh,
                                            half4* __restrict__ eh,
                                            float* __restrict__ esq) {
  int row = blockIdx.x * 4 + (threadIdx.x >> 6);
  int lane = threadIdx.x & 63;
  bool isE = row >= NB;
  int r = isE ? row - NB : row;
  float4 v = (isE ? e4 : z4)[(size_t)r * 64 + lane];
  half4 h;
  h.x = (_Float16)v.x;
  h.y = (_Float16)v.y;
  h.z = (_Float16)v.z;
  h.w = (_Float16)v.w;
  (isE ? eh : zh)[(size_t)r * 64 + lane] = h;
  if (isE) {
    double s = (double)v.x * v.x + (double)v.y * v.y + (double)v.z * v.z +
               (double)v.w * v.w;
#pragma unroll
    for (int sh = 1; sh < 64; sh <<= 1) s += __shfl_xor(s, sh, 64);
    if (lane == 0) esq[r] = (float)s;
  }
}

// ---- fused hi-only GEMM + per-chunk top-2 argmin ----
__global__ __launch_bounds__(256, 2) void gemm_argmin(
    const _Float16* __restrict__ zh, const _Float16* __restrict__ eh,
    const float* __restrict__ esq, ulonglong2* __restrict__ cand) {
  // combined tile: rows 0..127 each hold A-granules 0..3 | B-granules 4..7
  // (16B granules, 128B rows); granule c of row r stored at pos = c ^ (r&7).
  __shared__ __align__(16) _Float16 sT[128 * 64];   // 16 KB, static address
  const int tid = threadIdx.x;
  const int wave = tid >> 6, lane = tid & 63;
  const int bx = blockIdx.x, by = blockIdx.y;
  const int wr = wave >> 1, wc = wave & 1;
  const int row0 = by * 128, col0 = bx * 128;
  const int fr = lane & 15, g = lane >> 4;

  f32x4 acc[4][4] = {};

  for (int ks = 0; ks < 8; ++ks) {
    const int kc = ks * 32;
    // stage: 16 gload_lds16 across 4 waves, pre-swizzled per-lane source
#pragma unroll
    for (int i = 0; i < 4; ++i) {
      const int base = (wave * 4 + i) * 64;  // wave-uniform granule base
      const int L = base + lane;
      const int r = L >> 3, pos = L & 7, c = pos ^ (r & 7);
      const _Float16* src = (c < 4)
          ? zh + (size_t)(row0 + r) * ND + kc + c * 8
          : eh + (size_t)(col0 + r) * ND + kc + (c - 4) * 8;
      gload_lds16(src, &sT[(size_t)base * 8]);
    }
    __syncthreads();  // drains vmcnt(0): tile ready

    half8 a[4], b[4];
#pragma unroll
    for (int m = 0; m < 4; ++m) {
      int r = wr * 64 + m * 16 + fr;
      a[m] = *(const half8*)&sT[r * 64 + (g ^ (r & 7)) * 8];
      int rb = wc * 64 + m * 16 + fr;
      b[m] = *(const half8*)&sT[rb * 64 + (((4 + g) ^ (rb & 7))) * 8];
    }
#pragma unroll
    for (int m = 0; m < 4; ++m)
#pragma unroll
      for (int n = 0; n < 4; ++n)
        acc[m][n] =
            __builtin_amdgcn_mfma_f32_16x16x32_f16(a[m], b[n], acc[m][n], 0, 0, 0);
    __syncthreads();  // all waves done reading before next stage overwrites
  }

  // epilogue: key = e_sq[col] - 2*cross; keep top-2 per (row, 64-col chunk)
  float es[4];
#pragma unroll
  for (int n = 0; n < 4; ++n) es[n] = esq[col0 + wc * 64 + n * 16 + fr];
  const int chunkIdx = bx * 2 + wc;
#pragma unroll
  for (int m = 0; m < 4; ++m) {
#pragma unroll
    for (int j = 0; j < 4; ++j) {
      u64 b1 = ~0ull, b2 = ~0ull;
#pragma unroll
      for (int n = 0; n < 4; ++n) {
        float dist = es[n] - 2.0f * acc[m][n][j];
        unsigned int col = col0 + wc * 64 + n * 16 + fr;
        top2_ins(((u64)fkey(dist) << 32) | col, b1, b2);
      }
      top2_merge(1, b1, b2);
      top2_merge(2, b1, b2);
      top2_merge(4, b1, b2);
      top2_merge(8, b1, b2);
      if (fr == 0) {
        int row = row0 + wr * 64 + m * 16 + g * 4 + j;
        ulonglong2 p;
        p.x = b1;
        p.y = b2;
        cand[(size_t)row * NCHUNK + chunkIdx] = p;
      }
    }
  }
}

// ---- re-rank: per-wave top-2 of 64 entries -> 8 candidates, exact f64, gather ----
__global__ __launch_bounds__(256) void rerank(const u64* __restrict__ cand,
                                              const float4* __restrict__ z4,
                                              const float4* __restrict__ e4,
                                              const float* __restrict__ e,
                                              float* __restrict__ out) {
  const int row = blockIdx.x;
  const int tid = threadIdx.x, wave = tid >> 6, lane = tid & 63;
  __shared__ double sdist[8];
  __shared__ int sidx[8];
  __shared__ int sbest;

  u64 b1 = cand[(size_t)row * 256 + tid], b2 = ~0ull;
#pragma unroll
  for (int s = 1; s < 64; s <<= 1) top2_merge(s, b1, b2);
  const int c1 = (int)(b1 & 0xFFFFFFFFu), c2 = (int)(b2 & 0xFFFFFFFFu);

  float4 zv = z4[(size_t)row * 64 + lane];
#pragma unroll
  for (int t = 0; t < 2; ++t) {
    int idx = t ? c2 : c1;
    float4 ev = e4[(size_t)idx * 64 + lane];
    double dx = (double)zv.x - (double)ev.x;
    double dy = (double)zv.y - (double)ev.y;
    double dz = (double)zv.z - (double)ev.z;
    double dw = (double)zv.w - (double)ev.w;
    double s = dx * dx + dy * dy + dz * dz + dw * dw;
#pragma unroll
    for (int sh = 1; sh < 64; sh <<= 1) s += __shfl_xor(s, sh, 64);
    if (lane == 0) {
      sdist[wave * 2 + t] = s;
      sidx[wave * 2 + t] = idx;
    }
  }
  __syncthreads();
  if (tid == 0) {
    double bd = sdist[0];
    int bi = sidx[0];
    for (int w = 1; w < 8; ++w)
      if (sdist[w] < bd || (sdist[w] == bd && sidx[w] < bi)) {
        bd = sdist[w];
        bi = sidx[w];
      }
    sbest = bi;
  }
  __syncthreads();
  out[(size_t)row * ND + tid] = e[(size_t)sbest * ND + tid];
}

extern "C" void kernel_launch(void* const* d_in, const int* in_sizes, int n_in,
                              void* d_out, int out_size, void* d_ws, size_t ws_size,
                              hipStream_t stream) {
  const float* z = (const float*)d_in[0];
  const float* e = (const float*)d_in[1];
  float* out = (float*)d_out;
  char* ws = (char*)d_ws;

  _Float16* zh = (_Float16*)ws;                                     // 4 MB
  _Float16* eh = zh + (size_t)NB * ND;                              // 4 MB
  float* esq = (float*)(ws + 8u * 1024 * 1024);                     // 32 KB
  ulonglong2* cand = (ulonglong2*)(ws + 8u * 1024 * 1024 + 65536);  // 16 MB

  prep<<<(NB + NK) / 4, 256, 0, stream>>>((const float4*)z, (const float4*)e,
                                          (half4*)zh, (half4*)eh, esq);
  gemm_argmin<<<dim3(NK / 128, NB / 128), 256, 0, stream>>>(zh, eh, esq, cand);
  rerank<<<NB, 256, 0, stream>>>((const u64*)cand, (const float4*)z,
                                 (const float4*)e, e, out);
}

// Round 5
// 355.160 us; speedup vs baseline: 1.0096x; 1.0096x over previous
//
#include <hip/hip_runtime.h>
#include <hip/hip_bf16.h>
#include <stdint.h>

// VQ nearest-neighbor: B=8192 z-rows vs K=8192 codes, D=256 (f32 in/out).
// Round 5: round-2's EXACT staging structure (separate sAh/sBh tiles, each
// global_load_lds instruction sources ONE array -> clean VMEM coalescing),
// hi-only fp16 MFMA (16/step), top-2-per-64-col-chunk epilogue, exact f64
// re-rank of per-wave top-2 candidates, gather.

#define NB 8192
#define NK 8192
#define ND 256
#define NCHUNK (NK / 64)   // 128 chunks/row, 2 candidates each -> 256 entries

typedef __attribute__((ext_vector_type(4))) _Float16 half4;
typedef __attribute__((ext_vector_type(8))) _Float16 half8;
typedef __attribute__((ext_vector_type(4))) float f32x4;
typedef unsigned long long u64;

__device__ __forceinline__ unsigned int fkey(float f) {
  unsigned int i = __float_as_uint(f);
  return (i & 0x80000000u) ? ~i : (i | 0x80000000u);  // monotone f32 -> u32
}

__device__ __forceinline__ void gload_lds16(const void* g, void* l) {
  __builtin_amdgcn_global_load_lds(
      (const __attribute__((address_space(1))) unsigned int*)g,
      (__attribute__((address_space(3))) unsigned int*)l, 16, 0, 0);
}

__device__ __forceinline__ void top2_ins(u64 v, u64& b1, u64& b2) {
  if (v < b1) { b2 = b1; b1 = v; }
  else if (v < b2) { b2 = v; }
}

__device__ __forceinline__ void top2_merge(int s, u64& b1, u64& b2) {
  u64 p1 = __shfl_xor(b1, s, 64);
  u64 p2 = __shfl_xor(b2, s, 64);
  u64 hi = b1 > p1 ? b1 : p1;
  u64 lo2 = b2 < p2 ? b2 : p2;
  b1 = b1 < p1 ? b1 : p1;
  b2 = hi < lo2 ? hi : lo2;
}

// ---- prep: one wave per row; f32 -> f16 hi; e-rows also reduce e_sq (f64) ----
__global__ __launch_bounds__(256) void prep(const float4* __restrict__ z4,
                                            const float4* __restrict__ e4,
                                            half4* __restrict__ zh,
                                            half4* __restrict__ eh,
                                            float* __restrict__ esq) {
  int row = blockIdx.x * 4 + (threadIdx.x >> 6);
  int lane = threadIdx.x & 63;
  bool isE = row >= NB;
  int r = isE ? row - NB : row;
  float4 v = (isE ? e4 : z4)[(size_t)r * 64 + lane];
  half4 h;
  h.x = (_Float16)v.x;
  h.y = (_Float16)v.y;
  h.z = (_Float16)v.z;
  h.w = (_Float16)v.w;
  (isE ? eh : zh)[(size_t)r * 64 + lane] = h;
  if (isE) {
    double s = (double)v.x * v.x + (double)v.y * v.y + (double)v.z * v.z +
               (double)v.w * v.w;
#pragma unroll
    for (int sh = 1; sh < 64; sh <<= 1) s += __shfl_xor(s, sh, 64);
    if (lane == 0) esq[r] = (float)s;
  }
}

// ---- fused hi-only GEMM + per-chunk top-2 argmin (round-2 structure) ----
__global__ __launch_bounds__(256, 2) void gemm_argmin(
    const _Float16* __restrict__ zh, const _Float16* __restrict__ eh,
    const float* __restrict__ esq, ulonglong2* __restrict__ cand) {
  __shared__ __align__(16) _Float16 sAh[128 * 32];  // 8 KB
  __shared__ __align__(16) _Float16 sBh[128 * 32];  // 8 KB
  const int tid = threadIdx.x;
  const int wave = tid >> 6, lane = tid & 63;
  const int bx = blockIdx.x, by = blockIdx.y;
  const int wr = wave >> 1, wc = wave & 1;
  const int row0 = by * 128, col0 = bx * 128;
  const int fr = lane & 15, g = lane >> 4;

  f32x4 acc[4][4] = {};

  for (int ks = 0; ks < 8; ++ks) {
    const int kc = ks * 32;
    // stage: each instruction sources ONE array (16 x 64B segments, coalesced)
#pragma unroll
    for (int i = 0; i < 2; ++i) {
      const int base = wave * 128 + i * 64;     // wave-uniform 16B-chunk base
      const int chunk = base + lane;            // per-lane chunk id
      const int r = chunk >> 2, c8 = (chunk & 3) * 8;
      const size_t loff = (size_t)base * 8;     // LDS element offset
      gload_lds16(zh + (size_t)(row0 + r) * ND + kc + c8, sAh + loff);
      gload_lds16(eh + (size_t)(col0 + r) * ND + kc + c8, sBh + loff);
    }
    __syncthreads();  // drains vmcnt(0): tiles ready

    half8 a[4], b[4];
#pragma unroll
    for (int m = 0; m < 4; ++m) {
      int r = wr * 64 + m * 16 + fr;
      a[m] = *(const half8*)&sAh[r * 32 + g * 8];
      int c = wc * 64 + m * 16 + fr;
      b[m] = *(const half8*)&sBh[c * 32 + g * 8];
    }
#pragma unroll
    for (int m = 0; m < 4; ++m)
#pragma unroll
      for (int n = 0; n < 4; ++n)
        acc[m][n] =
            __builtin_amdgcn_mfma_f32_16x16x32_f16(a[m], b[n], acc[m][n], 0, 0, 0);
    __syncthreads();  // all waves done reading before next stage overwrites
  }

  // epilogue: key = e_sq[col] - 2*cross; keep top-2 per (row, 64-col chunk)
  float es[4];
#pragma unroll
  for (int n = 0; n < 4; ++n) es[n] = esq[col0 + wc * 64 + n * 16 + fr];
  const int chunkIdx = bx * 2 + wc;
#pragma unroll
  for (int m = 0; m < 4; ++m) {
#pragma unroll
    for (int j = 0; j < 4; ++j) {
      u64 b1 = ~0ull, b2 = ~0ull;
#pragma unroll
      for (int n = 0; n < 4; ++n) {
        float dist = es[n] - 2.0f * acc[m][n][j];
        unsigned int col = col0 + wc * 64 + n * 16 + fr;
        top2_ins(((u64)fkey(dist) << 32) | col, b1, b2);
      }
      top2_merge(1, b1, b2);
      top2_merge(2, b1, b2);
      top2_merge(4, b1, b2);
      top2_merge(8, b1, b2);
      if (fr == 0) {
        int row = row0 + wr * 64 + m * 16 + g * 4 + j;
        ulonglong2 p;
        p.x = b1;
        p.y = b2;
        cand[(size_t)row * NCHUNK + chunkIdx] = p;
      }
    }
  }
}

// ---- re-rank: per-wave top-2 of 64 entries -> 8 candidates, exact f64, gather ----
__global__ __launch_bounds__(256) void rerank(const u64* __restrict__ cand,
                                              const float4* __restrict__ z4,
                                              const float4* __restrict__ e4,
                                              const float* __restrict__ e,
                                              float* __restrict__ out) {
  const int row = blockIdx.x;
  const int tid = threadIdx.x, wave = tid >> 6, lane = tid & 63;
  __shared__ double sdist[8];
  __shared__ int sidx[8];
  __shared__ int sbest;

  u64 b1 = cand[(size_t)row * 256 + tid], b2 = ~0ull;
#pragma unroll
  for (int s = 1; s < 64; s <<= 1) top2_merge(s, b1, b2);
  const int c1 = (int)(b1 & 0xFFFFFFFFu), c2 = (int)(b2 & 0xFFFFFFFFu);

  float4 zv = z4[(size_t)row * 64 + lane];
#pragma unroll
  for (int t = 0; t < 2; ++t) {
    int idx = t ? c2 : c1;
    float4 ev = e4[(size_t)idx * 64 + lane];
    double dx = (double)zv.x - (double)ev.x;
    double dy = (double)zv.y - (double)ev.y;
    double dz = (double)zv.z - (double)ev.z;
    double dw = (double)zv.w - (double)ev.w;
    double s = dx * dx + dy * dy + dz * dz + dw * dw;
#pragma unroll
    for (int sh = 1; sh < 64; sh <<= 1) s += __shfl_xor(s, sh, 64);
    if (lane == 0) {
      sdist[wave * 2 + t] = s;
      sidx[wave * 2 + t] = idx;
    }
  }
  __syncthreads();
  if (tid == 0) {
    double bd = sdist[0];
    int bi = sidx[0];
    for (int w = 1; w < 8; ++w)
      if (sdist[w] < bd || (sdist[w] == bd && sidx[w] < bi)) {
        bd = sdist[w];
        bi = sidx[w];
      }
    sbest = bi;
  }
  __syncthreads();
  out[(size_t)row * ND + tid] = e[(size_t)sbest * ND + tid];
}

extern "C" void kernel_launch(void* const* d_in, const int* in_sizes, int n_in,
                              void* d_out, int out_size, void* d_ws, size_t ws_size,
                              hipStream_t stream) {
  const float* z = (const float*)d_in[0];
  const float* e = (const float*)d_in[1];
  float* out = (float*)d_out;
  char* ws = (char*)d_ws;

  _Float16* zh = (_Float16*)ws;                                     // 4 MB
  _Float16* eh = zh + (size_t)NB * ND;                              // 4 MB
  float* esq = (float*)(ws + 8u * 1024 * 1024);                     // 32 KB
  ulonglong2* cand = (ulonglong2*)(ws + 8u * 1024 * 1024 + 65536);  // 16 MB

  prep<<<(NB + NK) / 4, 256, 0, stream>>>((const float4*)z, (const float4*)e,
                                          (half4*)zh, (half4*)eh, esq);
  gemm_argmin<<<dim3(NK / 128, NB / 128), 256, 0, stream>>>(zh, eh, esq, cand);
  rerank<<<NB, 256, 0, stream>>>((const u64*)cand, (const float4*)z,
                                 (const float4*)e, e, out);
}